// Round 1
// 604.998 us; speedup vs baseline: 1.1120x; 1.1120x over previous
//
#include <hip/hip_runtime.h>

// ---------------------------------------------------------------------------
// LlamaAttention fwd: B=1, S=2048, HID=4096, NH=32, NKV=8, HD=128, GQA x4.
// fp32 in/out; bf16 MFMA internally.
// R4: replace m97-style gemm128 with phased counted-vmcnt GEMM (T2+T3+T4+T5):
//   - BM=128 x BN=256 x BK=64, 512 thr (8 waves, 2Mx4N), wave owns 64x64 out
//   - triple-buffered LDS (144 KiB): stage tile t+2 during tile t; tile-end
//     s_waitcnt vmcnt(6) forces only tile t+1's loads (issued a full tile
//     earlier) -> never drains freshly-issued loads (T4)
//   - 2 phases per K-tile (k-slice split), each {8 ds_read_b128 || 3
//     global_load_lds -> s_barrier -> setprio(1) 16 MFMA setprio(0) ->
//     s_barrier} (T3/T5)
//   - st_16x32 XOR swizzle: linear gl_lds dest + pre-swizzled global source
//     col + swizzled LDS read addr (T2, rule #21 both-sides involution)
// ---------------------------------------------------------------------------

typedef __bf16 bf16_t;
typedef bf16_t bf16x8_t __attribute__((ext_vector_type(8)));
typedef float f32x4_t __attribute__((ext_vector_type(4)));

#define S_LEN 2048
#define HID 4096
#define NH 32
#define NKV 8
#define HD 128
#define KV_DIM 1024
#define QKV_DIM 6144                 // 4096 q | 1024 k | 1024 v
#define SCALE 0.08838834764831845f   // 1/sqrt(128)

// -------- persistent device scratch ----------------------------------------
__device__ __align__(16) bf16_t g_hsb[(size_t)S_LEN * HID];
__device__ __align__(16) bf16_t g_wqkvT[(size_t)QKV_DIM * HID];  // [n][k]
__device__ __align__(16) bf16_t g_woT[(size_t)HID * HID];        // [n][k]
__device__ __align__(16) bf16_t g_qkv[(size_t)S_LEN * QKV_DIM];  // post-RoPE
__device__ __align__(16) bf16_t g_vT[(size_t)NKV * HD * S_LEN];  // [kvh][d][s]
__device__ __align__(16) bf16_t g_ao[(size_t)S_LEN * HID];       // attn out

// async global->LDS, 16B per lane; LDS dest is wave-uniform base + lane*16
__device__ __forceinline__ void gl_lds16(const bf16_t* g, bf16_t* l) {
  __builtin_amdgcn_global_load_lds(
      (const __attribute__((address_space(1))) void*)g,
      (__attribute__((address_space(3))) void*)l, 16, 0, 0);
}

// ---------------------------------------------------------------------------
__global__ __launch_bounds__(256) void cast_f32_bf16(
    const float* __restrict__ in, bf16_t* __restrict__ out)
{
  size_t i = ((size_t)blockIdx.x * 256 + threadIdx.x) * 8;
  float4 a = *(const float4*)(in + i);
  float4 b = *(const float4*)(in + i + 4);
  bf16x8_t r;
  r[0] = (bf16_t)a.x; r[1] = (bf16_t)a.y; r[2] = (bf16_t)a.z; r[3] = (bf16_t)a.w;
  r[4] = (bf16_t)b.x; r[5] = (bf16_t)b.y; r[6] = (bf16_t)b.z; r[7] = (bf16_t)b.w;
  *(bf16x8_t*)(out + i) = r;
}

// ---------------------------------------------------------------------------
// Transpose+cast: in fp32 [R][C] stride is -> out bf16 [C][R] stride os.
// ---------------------------------------------------------------------------
__global__ __launch_bounds__(256) void transpose_f32_bf16(
    const float* __restrict__ in, bf16_t* __restrict__ out, int is, int os)
{
  __shared__ __align__(16) bf16_t T[64 * 72];
  int r0 = blockIdx.x * 64, c0 = blockIdx.y * 64;
  int t = threadIdx.x;
#pragma unroll
  for (int it = 0; it < 2; ++it) {
    int idx = t + it * 256;
    int r = idx >> 3, c8 = (idx & 7) * 8;
    const float* p = in + (size_t)(r0 + r) * is + c0 + c8;
    float4 a = *(const float4*)p;
    float4 b = *(const float4*)(p + 4);
    bf16x8_t x;
    x[0] = (bf16_t)a.x; x[1] = (bf16_t)a.y; x[2] = (bf16_t)a.z; x[3] = (bf16_t)a.w;
    x[4] = (bf16_t)b.x; x[5] = (bf16_t)b.y; x[6] = (bf16_t)b.z; x[7] = (bf16_t)b.w;
    *(bf16x8_t*)(T + r * 72 + c8) = x;
  }
  __syncthreads();
#pragma unroll
  for (int it = 0; it < 2; ++it) {
    int idx = t + it * 256;
    int c = idx >> 3, r8 = (idx & 7) * 8;
    bf16x8_t x;
#pragma unroll
    for (int i = 0; i < 8; ++i) x[i] = T[(r8 + i) * 72 + c];
    *(bf16x8_t*)(out + (size_t)(c0 + c) * os + r0 + r8) = x;
  }
}

// ---------------------------------------------------------------------------
// bf16 batched transpose (V -> V^T per kv head).
// ---------------------------------------------------------------------------
__global__ __launch_bounds__(256) void transpose_bf16(
    const bf16_t* __restrict__ in, bf16_t* __restrict__ out,
    int is, int os, int in_b, int out_b)
{
  __shared__ __align__(16) bf16_t T[64 * 72];
  const bf16_t* inp = in + (size_t)blockIdx.z * in_b;
  bf16_t* outp = out + (size_t)blockIdx.z * out_b;
  int r0 = blockIdx.x * 64, c0 = blockIdx.y * 64;
  int t = threadIdx.x;
#pragma unroll
  for (int it = 0; it < 2; ++it) {
    int idx = t + it * 256;
    int r = idx >> 3, c8 = (idx & 7) * 8;
    *(bf16x8_t*)(T + r * 72 + c8) =
        *(const bf16x8_t*)(inp + (size_t)(r0 + r) * is + c0 + c8);
  }
  __syncthreads();
#pragma unroll
  for (int it = 0; it < 2; ++it) {
    int idx = t + it * 256;
    int c = idx >> 3, r8 = (idx & 7) * 8;
    bf16x8_t x;
#pragma unroll
    for (int i = 0; i < 8; ++i) x[i] = T[(r8 + i) * 72 + c];
    *(bf16x8_t*)(outp + (size_t)(c0 + c) * os + r0 + r8) = x;
  }
}

// ---------------------------------------------------------------------------
// Phased counted-vmcnt GEMM: C[M,N] = A[M,K] @ Bt[N,K]^T.
// BM=128, BN=256, BK=64. 512 threads = 8 waves (2M x 4N), each wave a 64x64
// output quadrant (4x4 16x16x32 MFMA frags). Triple-buffered LDS ring.
// ---------------------------------------------------------------------------
template <typename CT>
__global__ __launch_bounds__(512, 2) void gemm8p(
    const bf16_t* __restrict__ A, const bf16_t* __restrict__ Bt,
    CT* __restrict__ C, int K, int N)
{
  constexpr int BM = 128, BN = 256;
  constexpr int BUFE = (BM + BN) * 64;            // elements per ring buffer
  __shared__ __align__(16) bf16_t lds[3 * BUFE];  // 144 KiB
  const int t = threadIdx.x;
  const int wid = t >> 6, lane = t & 63;
  const int ln = lane & 15, lq = lane >> 4;
  const int wm = wid >> 2, wn = wid & 3;          // 2 x 4 wave grid
  const int m0 = blockIdx.x * BM, n0 = blockIdx.y * BN;

  // ---- read-side swizzle: byte ^= ((byte>>9)&1)<<5; bit9 == row bit2 == ln&4
  const int lane_xor = (ln & 4) << 3;
  // per-lane swizzled LDS read bases (bytes), row stride 128B:
  //   A frag (mi,kk): Rb + abase + mi*2048 + kk*64
  //   B frag (ni,kk): Bb + bbase + ni*2048 + kk*64
  const int abase = (((wm * 64 + ln) * 128 + lq * 16) ^ lane_xor);
  const int bbase = (((wn * 64 + ln) * 128 + lq * 16) ^ lane_xor);

  // ---- staging: issue i covers 64 rows; thread stages 16B of row srow.
  // LDS dest is linear (wave-uniform base + lane*16); global source column is
  // pre-swizzled with the same involution so swizzled reads see linear data.
  const int srow = t >> 3;                                  // 0..63
  const int scol = ((((t & 7) * 16) ^ ((srow & 4) << 3)) >> 1);  // elements
  const bf16_t* Ag0 = A + (size_t)(m0 + srow) * K + scol;
  const bf16_t* Ag1 = Ag0 + (size_t)64 * K;
  const bf16_t* Bg0 = Bt + (size_t)(n0 + srow) * K + scol;
  const bf16_t* Bg1 = Bg0 + (size_t)64 * K;
  const bf16_t* Bg2 = Bg0 + (size_t)128 * K;
  const bf16_t* Bg3 = Bg0 + (size_t)192 * K;
  const int swb = wid * 512;      // wave-uniform LDS staging offset (elements)

  // ---- prologue: stage K-tiles 0 and 1 (6 loads each; never drain to 0)
  {
    bf16_t* Lb = lds + swb;
    gl_lds16(Ag0, Lb);            gl_lds16(Ag1, Lb + 4096);
    gl_lds16(Bg0, Lb + 8192);     gl_lds16(Bg1, Lb + 12288);
    gl_lds16(Bg2, Lb + 16384);    gl_lds16(Bg3, Lb + 20480);
    Lb = lds + BUFE + swb;
    gl_lds16(Ag0 + 64, Lb);         gl_lds16(Ag1 + 64, Lb + 4096);
    gl_lds16(Bg0 + 64, Lb + 8192);  gl_lds16(Bg1 + 64, Lb + 12288);
    gl_lds16(Bg2 + 64, Lb + 16384); gl_lds16(Bg3 + 64, Lb + 20480);
  }
  asm volatile("s_waitcnt vmcnt(6)" ::: "memory");   // tile 0 resident
  __builtin_amdgcn_sched_barrier(0);
  __builtin_amdgcn_s_barrier();

  f32x4_t acc[4][4] = {};
  const int NT = K >> 6;
  for (int tt = 0; tt < NT; ++tt) {
    const char* Rb = (const char*)(lds + (tt % 3) * BUFE);
    const char* Bb = Rb + 16384;                    // B region (BM*64*2 bytes)
    bf16_t* Ls = lds + ((tt + 2) % 3) * BUFE + swb; // stage target: tile t+2
    const int k2 = (tt + 2) << 6;
    const bool stg = (tt + 2) < NT;
    bf16x8_t af[4], bfr[4];

    // ================= phase 0: k-slice 0 =================
#pragma unroll
    for (int mi = 0; mi < 4; ++mi)
      af[mi] = *(const bf16x8_t*)(Rb + abase + mi * 2048);
#pragma unroll
    for (int ni = 0; ni < 4; ++ni)
      bfr[ni] = *(const bf16x8_t*)(Bb + bbase + ni * 2048);
    if (stg) {                                      // first 3 of 6 loads
      gl_lds16(Ag0 + k2, Ls);
      gl_lds16(Ag1 + k2, Ls + 4096);
      gl_lds16(Bg0 + k2, Ls + 8192);
    }
    __builtin_amdgcn_s_barrier();
    __builtin_amdgcn_s_setprio(1);
#pragma unroll
    for (int mi = 0; mi < 4; ++mi)
#pragma unroll
      for (int ni = 0; ni < 4; ++ni)
        acc[mi][ni] = __builtin_amdgcn_mfma_f32_16x16x32_bf16(
            af[mi], bfr[ni], acc[mi][ni], 0, 0, 0);
    __builtin_amdgcn_s_setprio(0);
    __builtin_amdgcn_s_barrier();

    // ================= phase 1: k-slice 1 =================
#pragma unroll
    for (int mi = 0; mi < 4; ++mi)
      af[mi] = *(const bf16x8_t*)(Rb + abase + mi * 2048 + 64);
#pragma unroll
    for (int ni = 0; ni < 4; ++ni)
      bfr[ni] = *(const bf16x8_t*)(Bb + bbase + ni * 2048 + 64);
    if (stg) {                                      // last 3 of 6 loads
      gl_lds16(Bg1 + k2, Ls + 12288);
      gl_lds16(Bg2 + k2, Ls + 16384);
      gl_lds16(Bg3 + k2, Ls + 20480);
    }
    __builtin_amdgcn_s_barrier();
    __builtin_amdgcn_s_setprio(1);
#pragma unroll
    for (int mi = 0; mi < 4; ++mi)
#pragma unroll
      for (int ni = 0; ni < 4; ++ni)
        acc[mi][ni] = __builtin_amdgcn_mfma_f32_16x16x32_bf16(
            af[mi], bfr[ni], acc[mi][ni], 0, 0, 0);
    __builtin_amdgcn_s_setprio(0);

    // -------- tile end: counted drain (tile t+1 ready; t+2 stays in flight)
    if (tt + 2 < NT) {
      asm volatile("s_waitcnt vmcnt(6)" ::: "memory");
    } else {
      asm volatile("s_waitcnt vmcnt(0)" ::: "memory");
    }
    __builtin_amdgcn_sched_barrier(0);
    __builtin_amdgcn_s_barrier();
  }

  // ---- epilogue (proven C/D mapping: col=ln, row=lq*4+r)
#pragma unroll
  for (int mi = 0; mi < 4; ++mi)
#pragma unroll
    for (int ni = 0; ni < 4; ++ni)
#pragma unroll
      for (int r = 0; r < 4; ++r)
        C[(size_t)(m0 + wm * 64 + mi * 16 + lq * 4 + r) * N
          + n0 + wn * 64 + ni * 16 + ln] = (CT)acc[mi][ni][r];
}

// ---------------------------------------------------------------------------
// RoPE in-place on fused qkv layout [s][6144]; cos/sin fp32 [S][128].
// ---------------------------------------------------------------------------
__global__ __launch_bounds__(256) void rope_kernel(
    bf16_t* __restrict__ qkv, const float* __restrict__ cs,
    const float* __restrict__ sn)
{
  int idx = blockIdx.x * 256 + threadIdx.x;   // S*(NH+NKV)*64 threads exact
  int d = idx & 63;
  int h = (idx >> 6) % (NH + NKV);
  int s = idx / (64 * (NH + NKV));
  float c = cs[s * HD + d], si = sn[s * HD + d];
  bf16_t* base = qkv + (size_t)s * QKV_DIM +
                 ((h < NH) ? h * HD : HID + (h - NH) * HD);
  float x1 = (float)base[d], x2 = (float)base[d + 64];
  base[d]      = (bf16_t)(x1 * c - x2 * si);
  base[d + 64] = (bf16_t)(x2 * c + x1 * si);
}

// ---------------------------------------------------------------------------
// Flash attention, causal, GQA. BK=64 k-tile, 64 q-rows/block (16/wave).
// Longest-first dispatch: qb = 31 - bid/32, head = bid%32.
// ---------------------------------------------------------------------------
__global__ __launch_bounds__(256) void attn_kernel(
    const bf16_t* __restrict__ QKV, const bf16_t* __restrict__ VT,
    bf16_t* __restrict__ O)
{
  __shared__ __align__(16) bf16_t Ks[64 * 136];    // [kpos][d], pad 128->136
  __shared__ __align__(16) bf16_t Vs[128 * 72];    // [d][kpos], pad 64->72
  __shared__ __align__(16) bf16_t Ps[4 * 16 * 72]; // per-wave [16 q][64 k]
  int t = threadIdx.x, wave = t >> 6, lane = t & 63;
  int ln = lane & 15, lq = lane >> 4;
  int bid = blockIdx.x;
  int qb = (S_LEN / 64 - 1) - (bid >> 5);
  int head = bid & 31, kvh = head >> 2;
  int q0 = qb * 64;
  int qr = q0 + wave * 16 + ln;

  bf16x8_t qf[4];
#pragma unroll
  for (int kk = 0; kk < 4; ++kk)
    qf[kk] = *(const bf16x8_t*)(QKV + (size_t)qr * QKV_DIM + head * HD +
                                kk * 32 + lq * 8);

  f32x4_t oa[8] = {};
  float m_r[4] = {-1e30f, -1e30f, -1e30f, -1e30f};
  float l_r[4] = {0.f, 0.f, 0.f, 0.f};

  int krow = t >> 4, kdc = (t & 15) * 8;   // Ks staging: 16 rows/pass
  int vrow = t >> 3, vkc = (t & 7) * 8;    // Vs staging: 32 rows/pass
  const bf16_t* Kg = QKV + HID + (size_t)kvh * HD;
  const bf16_t* Vg = VT + (size_t)kvh * HD * S_LEN;

  for (int kt = 0; kt <= qb; ++kt) {
    int kb = kt * 64;
    __syncthreads();
#pragma unroll
    for (int p = 0; p < 4; ++p) {
      int r_ = p * 16 + krow;
      *(bf16x8_t*)(Ks + r_ * 136 + kdc) =
          *(const bf16x8_t*)(Kg + (size_t)(kb + r_) * QKV_DIM + kdc);
      int d_ = p * 32 + vrow;
      *(bf16x8_t*)(Vs + d_ * 72 + vkc) =
          *(const bf16x8_t*)(Vg + (size_t)d_ * S_LEN + kb + vkc);
    }
    __syncthreads();

    // S = Q @ K^T : 4 col-tiles x 4 k-chunks
    f32x4_t sv[4] = {};
#pragma unroll
    for (int nt = 0; nt < 4; ++nt)
#pragma unroll
      for (int kk = 0; kk < 4; ++kk) {
        bf16x8_t kf = *(const bf16x8_t*)(Ks + (nt * 16 + ln) * 136 +
                                         kk * 32 + lq * 8);
        sv[nt] = __builtin_amdgcn_mfma_f32_16x16x32_bf16(qf[kk], kf, sv[nt],
                                                         0, 0, 0);
      }

    float p_[4][4];                        // [nt][r]
    if (kt == qb) {                        // diagonal tile: mask (uniform br.)
#pragma unroll
      for (int nt = 0; nt < 4; ++nt)
#pragma unroll
        for (int r = 0; r < 4; ++r) {
          int rq = wave * 16 + lq * 4 + r;
          p_[nt][r] = (nt * 16 + ln <= rq) ? sv[nt][r] * SCALE : -1e30f;
        }
    } else {
#pragma unroll
      for (int nt = 0; nt < 4; ++nt)
#pragma unroll
        for (int r = 0; r < 4; ++r) p_[nt][r] = sv[nt][r] * SCALE;
    }

    float mx[4];
#pragma unroll
    for (int r = 0; r < 4; ++r)
      mx[r] = fmaxf(fmaxf(p_[0][r], p_[1][r]), fmaxf(p_[2][r], p_[3][r]));
#pragma unroll
    for (int off = 8; off >= 1; off >>= 1)
#pragma unroll
      for (int r = 0; r < 4; ++r) mx[r] = fmaxf(mx[r], __shfl_xor(mx[r], off, 64));

    float al[4], rs[4];
#pragma unroll
    for (int r = 0; r < 4; ++r) {
      float mn = fmaxf(m_r[r], mx[r]);
      al[r] = __expf(m_r[r] - mn);
      m_r[r] = mn;
      rs[r] = 0.f;
#pragma unroll
      for (int nt = 0; nt < 4; ++nt) {
        p_[nt][r] = __expf(p_[nt][r] - mn);
        rs[r] += p_[nt][r];
      }
    }
#pragma unroll
    for (int off = 8; off >= 1; off >>= 1)
#pragma unroll
      for (int r = 0; r < 4; ++r) rs[r] += __shfl_xor(rs[r], off, 64);
#pragma unroll
    for (int r = 0; r < 4; ++r) l_r[r] = l_r[r] * al[r] + rs[r];
#pragma unroll
    for (int dt = 0; dt < 8; ++dt)
#pragma unroll
      for (int r = 0; r < 4; ++r) oa[dt][r] *= al[r];

    // P: C/D layout -> per-wave LDS slice -> A-operand layout (no barrier)
    bf16_t* myP = Ps + wave * 16 * 72;
#pragma unroll
    for (int nt = 0; nt < 4; ++nt)
#pragma unroll
      for (int r = 0; r < 4; ++r)
        myP[(lq * 4 + r) * 72 + nt * 16 + ln] = (bf16_t)p_[nt][r];
    bf16x8_t pf0 = *(const bf16x8_t*)(myP + ln * 72 + lq * 8);
    bf16x8_t pf1 = *(const bf16x8_t*)(myP + ln * 72 + 32 + lq * 8);
#pragma unroll
    for (int dt = 0; dt < 8; ++dt) {
      bf16x8_t v0 = *(const bf16x8_t*)(Vs + (dt * 16 + ln) * 72 + lq * 8);
      bf16x8_t v1 = *(const bf16x8_t*)(Vs + (dt * 16 + ln) * 72 + 32 + lq * 8);
      oa[dt] = __builtin_amdgcn_mfma_f32_16x16x32_bf16(pf0, v0, oa[dt], 0, 0, 0);
      oa[dt] = __builtin_amdgcn_mfma_f32_16x16x32_bf16(pf1, v1, oa[dt], 0, 0, 0);
    }
  }

#pragma unroll
  for (int dt = 0; dt < 8; ++dt)
#pragma unroll
    for (int r = 0; r < 4; ++r) {
      int row = q0 + wave * 16 + lq * 4 + r;
      O[(size_t)row * HID + head * HD + dt * 16 + ln] =
          (bf16_t)(oa[dt][r] / l_r[r]);
    }
}

// ---------------------------------------------------------------------------
extern "C" void kernel_launch(void* const* d_in, const int* in_sizes, int n_in,
                              void* d_out, int out_size, void* d_ws, size_t ws_size,
                              hipStream_t stream)
{
  (void)in_sizes; (void)n_in; (void)out_size; (void)d_ws; (void)ws_size;
  const float* hs = (const float*)d_in[0];
  // d_in[1] = attention_mask (pure causal) -> analytic
  const float* wq = (const float*)d_in[2];
  const float* wk = (const float*)d_in[3];
  const float* wv = (const float*)d_in[4];
  const float* wo = (const float*)d_in[5];
  const float* cs = (const float*)d_in[6];
  const float* sn = (const float*)d_in[7];
  float* out = (float*)d_out;

  bf16_t *hsb, *wqkvT, *woT, *qkv, *vT, *ao;
  hipGetSymbolAddress((void**)&hsb,   HIP_SYMBOL(g_hsb));
  hipGetSymbolAddress((void**)&wqkvT, HIP_SYMBOL(g_wqkvT));
  hipGetSymbolAddress((void**)&woT,   HIP_SYMBOL(g_woT));
  hipGetSymbolAddress((void**)&qkv,   HIP_SYMBOL(g_qkv));
  hipGetSymbolAddress((void**)&vT,    HIP_SYMBOL(g_vT));
  hipGetSymbolAddress((void**)&ao,    HIP_SYMBOL(g_ao));

  // hidden_states fp32 -> bf16
  cast_f32_bf16<<<(S_LEN * HID) / (256 * 8), 256, 0, stream>>>(hs, hsb);

  // weight transposes (+cast) into fused wqkvT rows [0,4096,5120] and woT
  transpose_f32_bf16<<<dim3(64, 64), 256, 0, stream>>>(wq, wqkvT, HID, HID);
  transpose_f32_bf16<<<dim3(64, 16), 256, 0, stream>>>(
      wk, wqkvT + (size_t)HID * HID, KV_DIM, HID);
  transpose_f32_bf16<<<dim3(64, 16), 256, 0, stream>>>(
      wv, wqkvT + (size_t)(HID + KV_DIM) * HID, KV_DIM, HID);
  transpose_f32_bf16<<<dim3(64, 64), 256, 0, stream>>>(wo, woT, HID, HID);

  // fused QKV projection: [2048,4096] @ [6144,4096]^T -> [2048,6144]
  gemm8p<bf16_t><<<dim3(S_LEN / 128, QKV_DIM / 256), 512, 0, stream>>>(
      hsb, wqkvT, qkv, HID, QKV_DIM);

  // RoPE on q and k (in fused layout)
  rope_kernel<<<(S_LEN * (NH + NKV) * 64) / 256, 256, 0, stream>>>(qkv, cs, sn);

  // v section [s][kvh*128+d] -> vT[kvh][d][s]
  transpose_bf16<<<dim3(S_LEN / 64, HD / 64, NKV), 256, 0, stream>>>(
      qkv + HID + KV_DIM, vT, QKV_DIM, S_LEN, HD, HD * S_LEN);

  // attention (longest blocks first)
  attn_kernel<<<dim3((S_LEN / 64) * NH), 256, 0, stream>>>(qkv, vT, ao);

  // output projection (fp32 out)
  gemm8p<float><<<dim3(S_LEN / 128, HID / 256), 512, 0, stream>>>(
      ao, woT, out, HID, HID);
}